// Round 8
// baseline (299.864 us; speedup 1.0000x reference)
//
#include <hip/hip_runtime.h>
#include <cmath>

// GNNCASimple: x:[N,128] -> enc MLP -> h:[N,256] -> msg GEMM -> m:[N,256]
// -> segment_sum over E edges -> aggr:[N,256] -> dec(cat(aggr,h)) -> out:[N,128]
// N=50000, E=400000, D=128, H=256, steps=1.
//
// R2: CSR gather replaced atomic scatter (1907 -> 766 us).
// R3: bf16 MFMA GEMMs + bf16 activations (766 -> 532 us).
// R4/R5: hierarchical scan + CSR scratch in d_ws (532 -> 425 us).
// R6: 16B global_load_lds staging (425 -> 298 us).
// R7: gather unroll-4 + BK=64 (298 -> 285; BK=64 was a dud -- the drain
//     barrier sits right after the loads, latency fully exposed either way).
// R8: double-buffered K-loop (BK=32): issue next tile's global_load_lds, THEN
//     MFMA current tile, THEN barrier -- latency hidden behind compute.

typedef __attribute__((ext_vector_type(8))) short  short8;   // 8 bf16 (4 VGPR)
typedef __attribute__((ext_vector_type(4))) float  f32x4;    // MFMA acc
typedef __attribute__((ext_vector_type(4))) unsigned short us4;

typedef unsigned short u16;
typedef unsigned int   u32;

static __device__ __forceinline__ u16 f2bf(float f) {
    u32 u = __float_as_uint(f);
    u = (u + 0x7FFFu + ((u >> 16) & 1u)) >> 16;   // round-to-nearest-even
    return (u16)u;
}
static __device__ __forceinline__ float bf2f(u16 h) {
    return __uint_as_float(((u32)h) << 16);
}

// async 16B global -> LDS; lds base must be wave-uniform (+ lane*16 implicit).
static __device__ __forceinline__ void g2l16(const void* g, void* l) {
    __builtin_amdgcn_global_load_lds(
        (const __attribute__((address_space(1))) u32*)g,
        (__attribute__((address_space(3))) u32*)l, 16, 0, 0);
}

// ---------------- bf16 MFMA GEMM ----------------
// C[N,M] = act(A[N,K] @ W[M,K]^T + bias). A = concat(A0 cols [0,K0), A1 rest),
// both bf16. W bf16 [M,K]. bias fp32. ACT: 0=none 1=relu 2=tanh.
// Tile 128x128, BK=32, 256 threads (4 waves, each 64x64 = 4x4 MFMA tiles).
// LDS double-buffered, LINEAR [128][32] u16 per buffer (granule = 16 rows,
// 1 KB) per global_load_lds's wave-uniform-base + lane*16 rule.
template <int ACT, bool OUT_BF16>
__global__ __launch_bounds__(256) void gemm_bf16(
    const u16* __restrict__ A0, const u16* __restrict__ A1,
    const int K0, const int K,
    const u16* __restrict__ W, const float* __restrict__ bias,
    void* __restrict__ Cout, const int N, const int M)
{
    __shared__ u16 As[2][128 * 32];
    __shared__ u16 Ws[2][128 * 32];

    const int t    = threadIdx.x;
    const int c0   = blockIdx.x * 128;
    const int r0   = blockIdx.y * 128;
    const int wave = t >> 6;
    const int lane = t & 63;
    const int n    = lane & 15;       // fragment row index
    const int q    = lane >> 4;       // k-granule / acc row-quad
    const int wr   = (wave & 1) * 64;
    const int wc   = (wave >> 1) * 64;

    // staging: granule g covers tile rows [16g,16g+16); wave owns {wave, wave+4}
    const int grow0 = wave * 16 + (lane >> 2);
    const int grow1 = (wave + 4) * 16 + (lane >> 2);
    const int qofs  = (lane & 3) * 8;   // u16 offset within row (16 B chunk)

    const int KA1 = K - K0;
    const int ar0 = min(r0 + grow0, N - 1);   // clamp tail (junk, masked)
    const int ar1 = min(r0 + grow1, N - 1);
    const u16* a0b0 = A0 + (size_t)ar0 * K0 + qofs;
    const u16* a0b1 = A0 + (size_t)ar1 * K0 + qofs;
    const u16* a1b0 = A1 + (size_t)ar0 * KA1 + qofs;
    const u16* a1b1 = A1 + (size_t)ar1 * KA1 + qofs;
    const u16* wb0  = W + (size_t)(c0 + grow0) * K + qofs;
    const u16* wb1  = W + (size_t)(c0 + grow1) * K + qofs;

    f32x4 acc[4][4];
#pragma unroll
    for (int i = 0; i < 4; i++)
#pragma unroll
        for (int j = 0; j < 4; j++) acc[i][j] = (f32x4)0.0f;

    // prologue: stage tile kc=0 into buffer 0
    {
        if (0 < K0) {
            g2l16(a0b0, &As[0][wave * 512]);
            g2l16(a0b1, &As[0][(wave + 4) * 512]);
        } else {
            g2l16(a1b0, &As[0][wave * 512]);
            g2l16(a1b1, &As[0][(wave + 4) * 512]);
        }
        g2l16(wb0, &Ws[0][wave * 512]);
        g2l16(wb1, &Ws[0][(wave + 4) * 512]);
    }

    int buf = 0;
    for (int kc = 0; kc < K; kc += 32) {
        __syncthreads();   // drains my vmcnt (cur tile staged); all waves done
                           // reading the other buffer (safe to overwrite)
        const int kn = kc + 32;
        if (kn < K) {      // issue next tile into the other buffer
            const int nb = buf ^ 1;
            if (kn < K0) {
                g2l16(a0b0 + kn, &As[nb][wave * 512]);
                g2l16(a0b1 + kn, &As[nb][(wave + 4) * 512]);
            } else {
                g2l16(a1b0 + (kn - K0), &As[nb][wave * 512]);
                g2l16(a1b1 + (kn - K0), &As[nb][(wave + 4) * 512]);
            }
            g2l16(wb0 + kn, &Ws[nb][wave * 512]);
            g2l16(wb1 + kn, &Ws[nb][(wave + 4) * 512]);
        }

        short8 af[4], bf[4];
#pragma unroll
        for (int i = 0; i < 4; i++)
            af[i] = *reinterpret_cast<const short8*>(
                &As[buf][(wr + i * 16 + n) * 32 + q * 8]);
#pragma unroll
        for (int j = 0; j < 4; j++)
            bf[j] = *reinterpret_cast<const short8*>(
                &Ws[buf][(wc + j * 16 + n) * 32 + q * 8]);
#pragma unroll
        for (int i = 0; i < 4; i++)
#pragma unroll
            for (int j = 0; j < 4; j++)
                acc[i][j] = __builtin_amdgcn_mfma_f32_16x16x32_bf16(
                    af[i], bf[j], acc[i][j], 0, 0, 0);
        buf ^= 1;
    }

    float bv[4];
#pragma unroll
    for (int j = 0; j < 4; j++) bv[j] = bias[c0 + wc + j * 16 + n];

#pragma unroll
    for (int i = 0; i < 4; i++) {
        const int rbase = r0 + wr + i * 16 + q * 4;
#pragma unroll
        for (int reg = 0; reg < 4; reg++) {
            const int row = rbase + reg;
            if (row < N) {
#pragma unroll
                for (int j = 0; j < 4; j++) {
                    const int col = c0 + wc + j * 16 + n;
                    float v = acc[i][j][reg] + bv[j];
                    if (ACT == 1) v = fmaxf(v, 0.0f);
                    if (ACT == 2) v = tanhf(v);
                    if (OUT_BF16)
                        ((u16*)Cout)[(size_t)row * M + col] = f2bf(v);
                    else
                        ((float*)Cout)[(size_t)row * M + col] = v;
                }
            }
        }
    }
}

// ---------------- converts (single launch, 6 slices) ----------------
__global__ __launch_bounds__(256) void cvt6_kernel(
    const float* s0, const float* s1, const float* s2, const float* s3,
    const float* s4, const float* s5,
    u16* d0, u16* d1, u16* d2, u16* d3, u16* d4, u16* d5,
    int n0, int n1, int n2, int n3, int n4, int n5)
{
    const float* s; u16* d; int nq;
    switch (blockIdx.y) {
        case 0: s = s0; d = d0; nq = n0; break;
        case 1: s = s1; d = d1; nq = n1; break;
        case 2: s = s2; d = d2; nq = n2; break;
        case 3: s = s3; d = d3; nq = n3; break;
        case 4: s = s4; d = d4; nq = n4; break;
        default: s = s5; d = d5; nq = n5; break;
    }
    const int i = blockIdx.x * 256 + threadIdx.x;
    if (i < nq) {
        const float4 v = reinterpret_cast<const float4*>(s)[i];
        us4 o = { f2bf(v.x), f2bf(v.y), f2bf(v.z), f2bf(v.w) };
        reinterpret_cast<us4*>(d)[i] = o;
    }
}

// ---------------- CSR build (all scratch in d_ws) ----------------
__global__ __launch_bounds__(256) void zero_kernel(
    int* __restrict__ p, const int n)
{
    const int i = blockIdx.x * 256 + threadIdx.x;
    if (i < n) p[i] = 0;
}

__global__ __launch_bounds__(256) void histo_kernel(
    const int* __restrict__ ei, int* __restrict__ deg, const int E,
    const int Nn)
{
    const int e = blockIdx.x * 256 + threadIdx.x;
    if (e < E) {
        const int dst = ei[(size_t)E + e];
        if ((unsigned)dst < (unsigned)Nn) atomicAdd(&deg[dst], 1);
    }
}

__global__ __launch_bounds__(256) void scan_reduce_kernel(
    const int* __restrict__ deg, int* __restrict__ bsums, const int Nn)
{
    __shared__ int s[256];
    const int t = threadIdx.x;
    const int i = blockIdx.x * 256 + t;
    s[t] = (i < Nn) ? deg[i] : 0;
    __syncthreads();
    for (int d = 128; d > 0; d >>= 1) {
        if (t < d) s[t] += s[t + d];
        __syncthreads();
    }
    if (t == 0) bsums[blockIdx.x] = s[0];
}

__global__ __launch_bounds__(256) void scan_sums_kernel(
    const int* __restrict__ bsums, int* __restrict__ bscan, const int nb)
{
    __shared__ int s[256];
    const int t = threadIdx.x;
    const int v = (t < nb) ? bsums[t] : 0;
    s[t] = v;
    __syncthreads();
    for (int d = 1; d < 256; d <<= 1) {
        int u = (t >= d) ? s[t - d] : 0;
        __syncthreads();
        s[t] += u;
        __syncthreads();
    }
    if (t < nb) bscan[t] = s[t] - v;   // exclusive
}

__global__ __launch_bounds__(256) void scan_final_kernel(
    const int* __restrict__ deg, const int* __restrict__ bscan,
    int* __restrict__ offsets, int* __restrict__ cursor, const int Nn)
{
    __shared__ int s[256];
    const int t = threadIdx.x;
    const int i = blockIdx.x * 256 + t;
    const int v = (i < Nn) ? deg[i] : 0;
    s[t] = v;
    __syncthreads();
    for (int d = 1; d < 256; d <<= 1) {
        int u = (t >= d) ? s[t - d] : 0;
        __syncthreads();
        s[t] += u;
        __syncthreads();
    }
    const int excl = s[t] - v + bscan[blockIdx.x];
    if (i < Nn) {
        offsets[i] = excl;
        cursor[i]  = excl;
        if (i == Nn - 1) offsets[Nn] = excl + v;   // == E
    }
}

__global__ __launch_bounds__(256) void fill_kernel(
    const int* __restrict__ ei, int* __restrict__ cursor,
    int* __restrict__ bucket, const int E, const int Nn)
{
    const int e = blockIdx.x * 256 + threadIdx.x;
    if (e < E) {
        const int src = ei[e];
        const int dst = ei[(size_t)E + e];
        if ((unsigned)dst < (unsigned)Nn) {
            const int pos = atomicAdd(&cursor[dst], 1);
            if ((unsigned)pos < (unsigned)E) bucket[pos] = src;
        }
    }
}

// ---------------- gather-sum (bf16 m -> bf16 aggr) ----------------
__global__ __launch_bounds__(256) void gather_sum_kernel(
    const u16* __restrict__ m, const int* __restrict__ bucket,
    const int* __restrict__ offsets, u16* __restrict__ out,
    const int Nn, const int E)
{
    const int wave = (int)((blockIdx.x * 256u + threadIdx.x) >> 6);
    const int lane = threadIdx.x & 63;
    if (wave >= Nn) return;
    int beg = offsets[wave];
    int end = offsets[wave + 1];
    beg = max(0, min(beg, E));
    end = max(beg, min(end, E));
    float a0 = 0.f, a1 = 0.f, a2 = 0.f, a3 = 0.f;
    int e = beg;
    for (; e + 3 < end; e += 4) {
        int sidx[4];
#pragma unroll
        for (int u = 0; u < 4; u++) sidx[u] = bucket[e + u];
        us4 v[4];
#pragma unroll
        for (int u = 0; u < 4; u++) {
            const int s = ((unsigned)sidx[u] < (unsigned)Nn) ? sidx[u] : 0;
            v[u] = *reinterpret_cast<const us4*>(&m[(size_t)s * 256 + lane * 4]);
        }
#pragma unroll
        for (int u = 0; u < 4; u++) {
            if ((unsigned)sidx[u] < (unsigned)Nn) {
                a0 += bf2f(v[u].x); a1 += bf2f(v[u].y);
                a2 += bf2f(v[u].z); a3 += bf2f(v[u].w);
            }
        }
    }
    for (; e < end; e++) {
        const int s0 = bucket[e];
        if ((unsigned)s0 < (unsigned)Nn) {
            const us4 v0 = *reinterpret_cast<const us4*>(
                &m[(size_t)s0 * 256 + lane * 4]);
            a0 += bf2f(v0.x); a1 += bf2f(v0.y);
            a2 += bf2f(v0.z); a3 += bf2f(v0.w);
        }
    }
    us4 o = { f2bf(a0), f2bf(a1), f2bf(a2), f2bf(a3) };
    *reinterpret_cast<us4*>(&out[(size_t)wave * 256 + lane * 4]) = o;
}

extern "C" void kernel_launch(void* const* d_in, const int* in_sizes, int n_in,
                              void* d_out, int out_size, void* d_ws, size_t ws_size,
                              hipStream_t stream)
{
    const float* x      = (const float*)d_in[0];
    const int*   ei     = (const int*)d_in[1];   // [2][E]
    const float* enc_w1 = (const float*)d_in[3];
    const float* enc_b1 = (const float*)d_in[4];
    const float* enc_w2 = (const float*)d_in[5];
    const float* enc_b2 = (const float*)d_in[6];
    const float* msg_w  = (const float*)d_in[7];
    const float* msg_b  = (const float*)d_in[8];
    const float* dec_w1 = (const float*)d_in[9];
    const float* dec_b1 = (const float*)d_in[10];
    const float* dec_w2 = (const float*)d_in[11];
    const float* dec_b2 = (const float*)d_in[12];

    const int N = 50000, D = 128, H = 256;
    const int E = in_sizes[1] / 2;
    const int NB = (N + 255) / 256;   // 196 scan blocks

    // ws layout (u16 part ~141.5 MB, then int CSR part ~2.2 MB)
    u16* xb   = (u16*)d_ws;                 // [N,128]
    u16* h1   = xb   + (size_t)N * D;       // [N,256]
    u16* h    = h1   + (size_t)N * H;
    u16* m    = h    + (size_t)N * H;
    u16* aggr = m    + (size_t)N * H;
    u16* dbuf = aggr + (size_t)N * H;
    u16* w_enc1 = dbuf + (size_t)N * H;     // 256*128
    u16* w_enc2 = w_enc1 + 256 * 128;       // 256*256
    u16* w_msg  = w_enc2 + 256 * 256;       // 256*256
    u16* w_dec1 = w_msg  + 256 * 256;       // 256*512
    u16* w_dec2 = w_dec1 + 256 * 512;       // 128*256
    int* deg     = (int*)(w_dec2 + 128 * 256);  // [N]
    int* offsets = deg + N;                 // [N+1]
    int* cursor  = offsets + N + 1;         // [N]
    int* bucket  = cursor + N;              // [E]
    int* bsums   = bucket + E;              // [NB]
    int* bscan   = bsums + NB;              // [NB]

    const dim3 blk(256);
    const dim3 gridH(2, (N + 127) / 128);   // M=256
    const dim3 gridD(1, (N + 127) / 128);   // M=128
    const int eblk = (E + 255) / 256;

    // converts (x + 5 weights, one launch)
    cvt6_kernel<<<dim3((N * D / 4 + 255) / 256, 6), blk, 0, stream>>>(
        x, enc_w1, enc_w2, msg_w, dec_w1, dec_w2,
        xb, w_enc1, w_enc2, w_msg, w_dec1, w_dec2,
        N * D / 4, 256 * 128 / 4, 256 * 256 / 4, 256 * 256 / 4,
        256 * 512 / 4, 128 * 256 / 4);

    // CSR build
    zero_kernel<<<dim3(NB), blk, 0, stream>>>(deg, N);
    histo_kernel<<<dim3(eblk), blk, 0, stream>>>(ei, deg, E, N);
    scan_reduce_kernel<<<dim3(NB), blk, 0, stream>>>(deg, bsums, N);
    scan_sums_kernel<<<dim3(1), blk, 0, stream>>>(bsums, bscan, NB);
    scan_final_kernel<<<dim3(NB), blk, 0, stream>>>(deg, bscan, offsets,
                                                    cursor, N);
    fill_kernel<<<dim3(eblk), blk, 0, stream>>>(ei, cursor, bucket, E, N);

    // 1) h1 = relu(x @ enc_w1^T + b1)
    gemm_bf16<1, true><<<gridH, blk, 0, stream>>>(xb, xb, D, D, w_enc1, enc_b1,
                                                  h1, N, H);
    // 2) h = relu(h1 @ enc_w2^T + b2)
    gemm_bf16<1, true><<<gridH, blk, 0, stream>>>(h1, h1, H, H, w_enc2, enc_b2,
                                                  h, N, H);
    // 3) m = h @ msg_w^T + msg_b
    gemm_bf16<0, true><<<gridH, blk, 0, stream>>>(h, h, H, H, w_msg, msg_b,
                                                  m, N, H);
    // 4) aggr = segment_sum(m[src], dst)
    gather_sum_kernel<<<dim3((N * 64 + 255) / 256), blk, 0, stream>>>(
        m, bucket, offsets, aggr, N, E);
    // 5) d = relu(cat(aggr, h) @ dec_w1^T + b1), K=512 split at 256
    gemm_bf16<1, true><<<gridH, blk, 0, stream>>>(aggr, h, H, 2 * H, w_dec1,
                                                  dec_b1, dbuf, N, H);
    // 6) out = tanh(d @ dec_w2^T + b2) -- the ONLY write to d_out
    gemm_bf16<2, false><<<gridD, blk, 0, stream>>>(dbuf, dbuf, H, H, w_dec2,
                                                   dec_b2, (float*)d_out, N, D);
}

// Round 9
// 246.011 us; speedup vs baseline: 1.2189x; 1.2189x over previous
//
#include <hip/hip_runtime.h>
#include <cmath>

// GNNCASimple: x:[N,128] -> enc MLP -> h:[N,256] -> msg GEMM -> m:[N,256]
// -> segment_sum over E edges -> aggr:[N,256] -> dec(cat(aggr,h)) -> out:[N,128]
// N=50000, E=400000, D=128, H=256, steps=1.
//
// R2: CSR gather replaced atomic scatter (1907 -> 766 us).
// R3: bf16 MFMA GEMMs + bf16 activations (766 -> 532 us).
// R4/R5: hierarchical scan + CSR scratch in d_ws (532 -> 425 us).
// R6: 16B global_load_lds staging (425 -> 298 us).
// R7: gather unroll-4 + BK=64 (298 -> 285).
// R8: explicit LDS dbuf REGRESSED (300 us) -- confirms m99/m100: barrier
//     drains vmcnt regardless; single-buffer m97 loop is the plateau.
// R9: graph restructure: fuse enc GEMMs (h1 stays in LDS), fuse dec GEMMs
//     (d stays in LDS), scan-free CSR via fixed-capacity buckets (64/node,
//     deg~Poisson(8), P(>64)~1e-34). 14 dispatches -> 5; kills ~100 MB of
//     intermediate HBM round-trips and ~9 launch ramps.

typedef __attribute__((ext_vector_type(8))) short  short8;   // 8 bf16 (4 VGPR)
typedef __attribute__((ext_vector_type(4))) float  f32x4;    // MFMA acc
typedef __attribute__((ext_vector_type(4))) unsigned short us4;

typedef unsigned short u16;
typedef unsigned int   u32;

static __device__ __forceinline__ u16 f2bf(float f) {
    u32 u = __float_as_uint(f);
    u = (u + 0x7FFFu + ((u >> 16) & 1u)) >> 16;   // round-to-nearest-even
    return (u16)u;
}
static __device__ __forceinline__ float bf2f(u16 h) {
    return __uint_as_float(((u32)h) << 16);
}

// async 16B global -> LDS; lds base wave-uniform (+ lane*16 implicit).
static __device__ __forceinline__ void g2l16(const void* g, void* l) {
    __builtin_amdgcn_global_load_lds(
        (const __attribute__((address_space(1))) u32*)g,
        (__attribute__((address_space(3))) u32*)l, 16, 0, 0);
}

// ---------------- fused encoder: x -> h, m ----------------
// Per block: 64 rows. Phase1: h1 = relu(x W1^T+b1) (K=128) kept in LDS.
// Phase2: h = relu(h1 W2^T+b2) (K=256, A from LDS) -> global + LDS.
// Phase3: m = h Wm^T+bm -> global.
// 4 waves, each 64 rows x 64 cols (wc=wave*64) of the 256-wide output.
// LDS: As 4KB + Ws 16KB + hL 32KB = 52KB -> up to 3 blocks/CU.
// hL chunk layout [8][64][32] == the proven staging layout, so phase-2/3
// fragment reads are byte-identical to the proven As read pattern.
__global__ __launch_bounds__(256, 2) void enc_fused(
    const u16* __restrict__ xb, const u16* __restrict__ w1,
    const float* __restrict__ b1, const u16* __restrict__ w2,
    const float* __restrict__ b2, const u16* __restrict__ wm,
    const float* __restrict__ bm, u16* __restrict__ hout,
    u16* __restrict__ mout, const int N)
{
    __shared__ u16 As[64 * 32];
    __shared__ u16 Ws[256 * 32];
    __shared__ u16 hL[8][64 * 32];

    const int t    = threadIdx.x;
    const int r0   = blockIdx.x * 64;
    const int wave = t >> 6;
    const int lane = t & 63;
    const int n    = lane & 15;
    const int q    = lane >> 4;
    const int wc   = wave * 64;
    const int lrow = lane >> 2;        // row within 16-row granule
    const int qofs = (lane & 3) * 8;   // u16 col offset (16B chunks)

    const int arow = min(r0 + wave * 16 + lrow, N - 1);  // tail clamp
    const u16* aptr = xb + (size_t)arow * 128 + qofs;

    int wrow[4];
#pragma unroll
    for (int k2 = 0; k2 < 4; k2++) wrow[k2] = (wave + 4 * k2) * 16 + lrow;

    f32x4 acc[4][4];
#pragma unroll
    for (int i = 0; i < 4; i++)
#pragma unroll
        for (int j = 0; j < 4; j++) acc[i][j] = (f32x4)0.0f;

    // ---- phase 1: K=128 ----
    for (int kc = 0; kc < 128; kc += 32) {
        __syncthreads();
        g2l16(aptr + kc, &As[wave * 512]);
#pragma unroll
        for (int k2 = 0; k2 < 4; k2++)
            g2l16(w1 + (size_t)wrow[k2] * 128 + kc + qofs,
                  &Ws[(wave + 4 * k2) * 512]);
        __syncthreads();
        short8 af[4], bf[4];
#pragma unroll
        for (int i = 0; i < 4; i++)
            af[i] = *reinterpret_cast<const short8*>(&As[(i * 16 + n) * 32 + q * 8]);
#pragma unroll
        for (int j = 0; j < 4; j++)
            bf[j] = *reinterpret_cast<const short8*>(&Ws[(wc + j * 16 + n) * 32 + q * 8]);
#pragma unroll
        for (int i = 0; i < 4; i++)
#pragma unroll
            for (int j = 0; j < 4; j++)
                acc[i][j] = __builtin_amdgcn_mfma_f32_16x16x32_bf16(
                    af[i], bf[j], acc[i][j], 0, 0, 0);
    }
    // epilogue -> hL (region untouched so far; no barrier needed before)
    {
        float bv[4];
#pragma unroll
        for (int j = 0; j < 4; j++) bv[j] = b1[wc + j * 16 + n];
#pragma unroll
        for (int i = 0; i < 4; i++)
#pragma unroll
            for (int reg = 0; reg < 4; reg++) {
                const int row = i * 16 + q * 4 + reg;
#pragma unroll
                for (int j = 0; j < 4; j++) {
                    const int col = wc + j * 16 + n;
                    const float v = fmaxf(acc[i][j][reg] + bv[j], 0.0f);
                    hL[col >> 5][row * 32 + (col & 31)] = f2bf(v);
                }
            }
    }

    // ---- phase 2: K=256, A from hL ----
#pragma unroll
    for (int i = 0; i < 4; i++)
#pragma unroll
        for (int j = 0; j < 4; j++) acc[i][j] = (f32x4)0.0f;
    for (int c = 0; c < 8; c++) {
        __syncthreads();   // hL writes visible; Ws free
#pragma unroll
        for (int k2 = 0; k2 < 4; k2++)
            g2l16(w2 + (size_t)wrow[k2] * 256 + c * 32 + qofs,
                  &Ws[(wave + 4 * k2) * 512]);
        __syncthreads();
        short8 af[4], bf[4];
#pragma unroll
        for (int i = 0; i < 4; i++)
            af[i] = *reinterpret_cast<const short8*>(&hL[c][(i * 16 + n) * 32 + q * 8]);
#pragma unroll
        for (int j = 0; j < 4; j++)
            bf[j] = *reinterpret_cast<const short8*>(&Ws[(wc + j * 16 + n) * 32 + q * 8]);
#pragma unroll
        for (int i = 0; i < 4; i++)
#pragma unroll
            for (int j = 0; j < 4; j++)
                acc[i][j] = __builtin_amdgcn_mfma_f32_16x16x32_bf16(
                    af[i], bf[j], acc[i][j], 0, 0, 0);
    }
    // epilogue: h -> global, then (after barrier) hL overwrite
    {
        float bv[4];
#pragma unroll
        for (int j = 0; j < 4; j++) bv[j] = b2[wc + j * 16 + n];
#pragma unroll
        for (int i = 0; i < 4; i++)
#pragma unroll
            for (int reg = 0; reg < 4; reg++) {
                const int row = r0 + i * 16 + q * 4 + reg;
                if (row < N) {
#pragma unroll
                    for (int j = 0; j < 4; j++) {
                        const float v = fmaxf(acc[i][j][reg] + bv[j], 0.0f);
                        hout[(size_t)row * 256 + wc + j * 16 + n] = f2bf(v);
                    }
                }
            }
        __syncthreads();   // all waves done reading hL (phase 2)
#pragma unroll
        for (int i = 0; i < 4; i++)
#pragma unroll
            for (int reg = 0; reg < 4; reg++) {
                const int row = i * 16 + q * 4 + reg;
#pragma unroll
                for (int j = 0; j < 4; j++) {
                    const int col = wc + j * 16 + n;
                    const float v = fmaxf(acc[i][j][reg] + bv[j], 0.0f);
                    hL[col >> 5][row * 32 + (col & 31)] = f2bf(v);
                }
            }
    }

    // ---- phase 3: m = h Wm^T + bm ----
#pragma unroll
    for (int i = 0; i < 4; i++)
#pragma unroll
        for (int j = 0; j < 4; j++) acc[i][j] = (f32x4)0.0f;
    for (int c = 0; c < 8; c++) {
        __syncthreads();
#pragma unroll
        for (int k2 = 0; k2 < 4; k2++)
            g2l16(wm + (size_t)wrow[k2] * 256 + c * 32 + qofs,
                  &Ws[(wave + 4 * k2) * 512]);
        __syncthreads();
        short8 af[4], bf[4];
#pragma unroll
        for (int i = 0; i < 4; i++)
            af[i] = *reinterpret_cast<const short8*>(&hL[c][(i * 16 + n) * 32 + q * 8]);
#pragma unroll
        for (int j = 0; j < 4; j++)
            bf[j] = *reinterpret_cast<const short8*>(&Ws[(wc + j * 16 + n) * 32 + q * 8]);
#pragma unroll
        for (int i = 0; i < 4; i++)
#pragma unroll
            for (int j = 0; j < 4; j++)
                acc[i][j] = __builtin_amdgcn_mfma_f32_16x16x32_bf16(
                    af[i], bf[j], acc[i][j], 0, 0, 0);
    }
    {
        float bv[4];
#pragma unroll
        for (int j = 0; j < 4; j++) bv[j] = bm[wc + j * 16 + n];
#pragma unroll
        for (int i = 0; i < 4; i++)
#pragma unroll
            for (int reg = 0; reg < 4; reg++) {
                const int row = r0 + i * 16 + q * 4 + reg;
                if (row < N) {
#pragma unroll
                    for (int j = 0; j < 4; j++)
                        mout[(size_t)row * 256 + wc + j * 16 + n] =
                            f2bf(acc[i][j][reg] + bv[j]);
                }
            }
    }
}

// ---------------- fused decoder: aggr,h -> out ----------------
// Phase A: d = relu(cat(aggr,h) Wd1^T + bd1), K=512 -> dL (LDS only).
// Phase B: out = tanh(d Wd2^T + bd2), K=256 from dL, M=128 (wave = 64x32).
__global__ __launch_bounds__(256, 2) void dec_fused(
    const u16* __restrict__ aggr, const u16* __restrict__ h,
    const u16* __restrict__ wd1, const float* __restrict__ bd1,
    const u16* __restrict__ wd2, const float* __restrict__ bd2,
    float* __restrict__ out, const int N)
{
    __shared__ u16 As[64 * 32];
    __shared__ u16 Ws[256 * 32];
    __shared__ u16 dL[8][64 * 32];

    const int t    = threadIdx.x;
    const int r0   = blockIdx.x * 64;
    const int wave = t >> 6;
    const int lane = t & 63;
    const int n    = lane & 15;
    const int q    = lane >> 4;
    const int wc   = wave * 64;
    const int lrow = lane >> 2;
    const int qofs = (lane & 3) * 8;

    const int arow = min(r0 + wave * 16 + lrow, N - 1);
    const u16* ap0 = aggr + (size_t)arow * 256 + qofs;
    const u16* ap1 = h    + (size_t)arow * 256 + qofs;

    int wrow[4];
#pragma unroll
    for (int k2 = 0; k2 < 4; k2++) wrow[k2] = (wave + 4 * k2) * 16 + lrow;

    f32x4 acc[4][4];
#pragma unroll
    for (int i = 0; i < 4; i++)
#pragma unroll
        for (int j = 0; j < 4; j++) acc[i][j] = (f32x4)0.0f;

    // ---- phase A: K=512 (cat split at 256) ----
    for (int kc = 0; kc < 512; kc += 32) {
        __syncthreads();
        if (kc < 256) g2l16(ap0 + kc, &As[wave * 512]);
        else          g2l16(ap1 + (kc - 256), &As[wave * 512]);
#pragma unroll
        for (int k2 = 0; k2 < 4; k2++)
            g2l16(wd1 + (size_t)wrow[k2] * 512 + kc + qofs,
                  &Ws[(wave + 4 * k2) * 512]);
        __syncthreads();
        short8 af[4], bf[4];
#pragma unroll
        for (int i = 0; i < 4; i++)
            af[i] = *reinterpret_cast<const short8*>(&As[(i * 16 + n) * 32 + q * 8]);
#pragma unroll
        for (int j = 0; j < 4; j++)
            bf[j] = *reinterpret_cast<const short8*>(&Ws[(wc + j * 16 + n) * 32 + q * 8]);
#pragma unroll
        for (int i = 0; i < 4; i++)
#pragma unroll
            for (int j = 0; j < 4; j++)
                acc[i][j] = __builtin_amdgcn_mfma_f32_16x16x32_bf16(
                    af[i], bf[j], acc[i][j], 0, 0, 0);
    }
    // epilogue -> dL
    {
        float bv[4];
#pragma unroll
        for (int j = 0; j < 4; j++) bv[j] = bd1[wc + j * 16 + n];
#pragma unroll
        for (int i = 0; i < 4; i++)
#pragma unroll
            for (int reg = 0; reg < 4; reg++) {
                const int row = i * 16 + q * 4 + reg;
#pragma unroll
                for (int j = 0; j < 4; j++) {
                    const int col = wc + j * 16 + n;
                    const float v = fmaxf(acc[i][j][reg] + bv[j], 0.0f);
                    dL[col >> 5][row * 32 + (col & 31)] = f2bf(v);
                }
            }
    }

    // ---- phase B: out 64x128, K=256 from dL ----
    f32x4 acc2[4][2];
#pragma unroll
    for (int i = 0; i < 4; i++)
#pragma unroll
        for (int j = 0; j < 2; j++) acc2[i][j] = (f32x4)0.0f;
    const int wc2 = wave * 32;
    for (int c = 0; c < 8; c++) {
        __syncthreads();   // dL writes visible; Ws free
        g2l16(wd2 + (size_t)(wave * 16 + lrow) * 256 + c * 32 + qofs,
              &Ws[wave * 512]);
        g2l16(wd2 + (size_t)((wave + 4) * 16 + lrow) * 256 + c * 32 + qofs,
              &Ws[(wave + 4) * 512]);
        __syncthreads();
        short8 af[4], bf[2];
#pragma unroll
        for (int i = 0; i < 4; i++)
            af[i] = *reinterpret_cast<const short8*>(&dL[c][(i * 16 + n) * 32 + q * 8]);
#pragma unroll
        for (int j = 0; j < 2; j++)
            bf[j] = *reinterpret_cast<const short8*>(&Ws[(wc2 + j * 16 + n) * 32 + q * 8]);
#pragma unroll
        for (int i = 0; i < 4; i++)
#pragma unroll
            for (int j = 0; j < 2; j++)
                acc2[i][j] = __builtin_amdgcn_mfma_f32_16x16x32_bf16(
                    af[i], bf[j], acc2[i][j], 0, 0, 0);
    }
    {
        float bv[2];
#pragma unroll
        for (int j = 0; j < 2; j++) bv[j] = bd2[wc2 + j * 16 + n];
#pragma unroll
        for (int i = 0; i < 4; i++)
#pragma unroll
            for (int reg = 0; reg < 4; reg++) {
                const int row = r0 + i * 16 + q * 4 + reg;
                if (row < N) {
#pragma unroll
                    for (int j = 0; j < 2; j++)
                        out[(size_t)row * 128 + wc2 + j * 16 + n] =
                            tanhf(acc2[i][j][reg] + bv[j]);
                }
            }
    }
}

// ---------------- converts + cursor zero (one dispatch, 7 slices) ----------
__global__ __launch_bounds__(256) void cvt7_kernel(
    const float* s0, const float* s1, const float* s2, const float* s3,
    const float* s4, const float* s5,
    u16* d0, u16* d1, u16* d2, u16* d3, u16* d4, u16* d5,
    int* __restrict__ zp,
    int n0, int n1, int n2, int n3, int n4, int n5, int nz)
{
    const int i = blockIdx.x * 256 + threadIdx.x;
    if (blockIdx.y == 6) {
        if (i < nz) zp[i] = 0;
        return;
    }
    const float* s; u16* d; int nq;
    switch (blockIdx.y) {
        case 0: s = s0; d = d0; nq = n0; break;
        case 1: s = s1; d = d1; nq = n1; break;
        case 2: s = s2; d = d2; nq = n2; break;
        case 3: s = s3; d = d3; nq = n3; break;
        case 4: s = s4; d = d4; nq = n4; break;
        default: s = s5; d = d5; nq = n5; break;
    }
    if (i < nq) {
        const float4 v = reinterpret_cast<const float4*>(s)[i];
        us4 o = { f2bf(v.x), f2bf(v.y), f2bf(v.z), f2bf(v.w) };
        reinterpret_cast<us4*>(d)[i] = o;
    }
}

// ---------------- scan-free bucket fill ----------------
// Fixed capacity 64 slots/node; deg ~ Poisson(8) => overflow prob ~1e-34.
__global__ __launch_bounds__(256) void fill_kernel(
    const int* __restrict__ ei, int* __restrict__ cursor,
    int* __restrict__ bucket, const int E, const int Nn)
{
    const int e = blockIdx.x * 256 + threadIdx.x;
    if (e < E) {
        const int src = ei[e];
        const int dst = ei[(size_t)E + e];
        if ((unsigned)dst < (unsigned)Nn) {
            const int pos = atomicAdd(&cursor[dst], 1);
            if (pos < 64) bucket[(size_t)dst * 64 + pos] = src;
        }
    }
}

// ---------------- gather-sum (bf16 m -> bf16 aggr) ----------------
__global__ __launch_bounds__(256) void gather_sum_kernel(
    const u16* __restrict__ m, const int* __restrict__ bucket,
    const int* __restrict__ cursor, u16* __restrict__ outa, const int Nn)
{
    const int wave = (int)((blockIdx.x * 256u + threadIdx.x) >> 6);
    const int lane = threadIdx.x & 63;
    if (wave >= Nn) return;
    const int cnt = min(cursor[wave], 64);
    const int* bl = bucket + (size_t)wave * 64;
    float a0 = 0.f, a1 = 0.f, a2 = 0.f, a3 = 0.f;
    int i = 0;
    for (; i + 3 < cnt; i += 4) {
        int sidx[4];
#pragma unroll
        for (int u = 0; u < 4; u++) sidx[u] = bl[i + u];
        us4 v[4];
#pragma unroll
        for (int u = 0; u < 4; u++) {
            const int s = ((unsigned)sidx[u] < (unsigned)Nn) ? sidx[u] : 0;
            v[u] = *reinterpret_cast<const us4*>(&m[(size_t)s * 256 + lane * 4]);
        }
#pragma unroll
        for (int u = 0; u < 4; u++) {
            if ((unsigned)sidx[u] < (unsigned)Nn) {
                a0 += bf2f(v[u].x); a1 += bf2f(v[u].y);
                a2 += bf2f(v[u].z); a3 += bf2f(v[u].w);
            }
        }
    }
    for (; i < cnt; i++) {
        const int s0 = bl[i];
        if ((unsigned)s0 < (unsigned)Nn) {
            const us4 v0 = *reinterpret_cast<const us4*>(
                &m[(size_t)s0 * 256 + lane * 4]);
            a0 += bf2f(v0.x); a1 += bf2f(v0.y);
            a2 += bf2f(v0.z); a3 += bf2f(v0.w);
        }
    }
    us4 o = { f2bf(a0), f2bf(a1), f2bf(a2), f2bf(a3) };
    *reinterpret_cast<us4*>(&outa[(size_t)wave * 256 + lane * 4]) = o;
}

extern "C" void kernel_launch(void* const* d_in, const int* in_sizes, int n_in,
                              void* d_out, int out_size, void* d_ws, size_t ws_size,
                              hipStream_t stream)
{
    const float* x      = (const float*)d_in[0];
    const int*   ei     = (const int*)d_in[1];   // [2][E]
    const float* enc_w1 = (const float*)d_in[3];
    const float* enc_b1 = (const float*)d_in[4];
    const float* enc_w2 = (const float*)d_in[5];
    const float* enc_b2 = (const float*)d_in[6];
    const float* msg_w  = (const float*)d_in[7];
    const float* msg_b  = (const float*)d_in[8];
    const float* dec_w1 = (const float*)d_in[9];
    const float* dec_b1 = (const float*)d_in[10];
    const float* dec_w2 = (const float*)d_in[11];
    const float* dec_b2 = (const float*)d_in[12];

    const int N = 50000, D = 128, H = 256;
    const int E = in_sizes[1] / 2;

    // ws layout: u16 slabs (~90.5 MB) then int CSR (~13 MB); total ~103.5 MB.
    u16* xb   = (u16*)d_ws;                  // [N,128]
    u16* h    = xb   + (size_t)N * D;        // [N,256]
    u16* m    = h    + (size_t)N * H;        // [N,256]
    u16* aggr = m    + (size_t)N * H;        // [N,256]
    u16* w1   = aggr + (size_t)N * H;        // 256*128
    u16* w2   = w1 + 256 * 128;              // 256*256
    u16* wm   = w2 + 256 * 256;              // 256*256
    u16* wd1  = wm + 256 * 256;              // 256*512
    u16* wd2  = wd1 + 256 * 512;             // 128*256
    int* cursor = (int*)(wd2 + 128 * 256);   // [N]
    int* bucket = cursor + N;                // [N*64]

    const dim3 blk(256);
    const int nb64 = (N + 63) / 64;          // 782 row blocks

    // 1) converts (x + 5 weights) + cursor zero
    cvt7_kernel<<<dim3((N * D / 4 + 255) / 256, 7), blk, 0, stream>>>(
        x, enc_w1, enc_w2, msg_w, dec_w1, dec_w2,
        xb, w1, w2, wm, wd1, wd2, cursor,
        N * D / 4, 256 * 128 / 4, 256 * 256 / 4, 256 * 256 / 4,
        256 * 512 / 4, 128 * 256 / 4, N);

    // 2) bucket fill (scan-free CSR)
    fill_kernel<<<dim3((E + 255) / 256), blk, 0, stream>>>(
        ei, cursor, bucket, E, N);

    // 3) fused encoder: x -> h, m
    enc_fused<<<dim3(nb64), blk, 0, stream>>>(
        xb, w1, enc_b1, w2, enc_b2, wm, msg_b, h, m, N);

    // 4) aggr = segment_sum(m[src], dst)
    gather_sum_kernel<<<dim3((N * 64 + 255) / 256), blk, 0, stream>>>(
        m, bucket, cursor, aggr, N);

    // 5) fused decoder: cat(aggr,h) -> out (ONLY write to d_out)
    dec_fused<<<dim3(nb64), blk, 0, stream>>>(
        aggr, h, wd1, dec_b1, wd2, dec_b2, (float*)d_out, N);
}